// Round 6
// baseline (1534.348 us; speedup 1.0000x reference)
//
#include <hip/hip_runtime.h>
#include <hip/hip_fp16.h>
#include <math.h>

// Problem constants (from reference): N nodes, E edges, D features.
constexpr int NN = 100000;
constexpr int NE = 1600000;
constexpr int D  = 128;
constexpr float SLOPE = 0.2f;
constexpr int BUCK_SHIFT = 5;              // 32 nodes per bucket
constexpr int NBUCK = NN >> BUCK_SHIFT;    // 3125, exact (100000 = 3125*32)

// ---------------------------------------------------------------------------
// Fused GEMM + s/t + fp16 pack (unchanged from R4 — verified passing).
//   acc = x[64rows] @ W[:,64cols]; h2 = fp16(acc); s,t += acc . a1/a2 slices.
// ---------------------------------------------------------------------------
__global__ __launch_bounds__(256) void gemm_xw(const float* __restrict__ x,
                                               const float* __restrict__ W,
                                               const float* __restrict__ a,
                                               __half* __restrict__ h2,
                                               float* __restrict__ s,
                                               float* __restrict__ t) {
    __shared__ float xsT[128 * 64];
    __shared__ float Ws [128 * 64];
    const int tid   = threadIdx.x;
    const int rbase = blockIdx.x * 64;
    const int cbase = blockIdx.y * 64;

#pragma unroll
    for (int i = 0; i < 8; ++i) {
        const int f = tid + i * 256;
        const int k = f >> 4;
        const int c = (f & 15) << 2;
        const float4 w = *reinterpret_cast<const float4*>(W + k * D + cbase + c);
        *reinterpret_cast<float4*>(Ws + k * 64 + c) = w;
    }
#pragma unroll
    for (int i = 0; i < 8; ++i) {
        const int f  = tid + i * 256;
        const int r  = f >> 5;
        const int c4 = f & 31;
        const int k0 = c4 << 2;
        float4 v = make_float4(0.f, 0.f, 0.f, 0.f);
        const int row = rbase + r;
        if (row < NN) v = *reinterpret_cast<const float4*>(x + (size_t)row * D + k0);
        const int rs_ = r ^ ((c4 & 7) << 2);
        xsT[(k0 + 0) * 64 + rs_] = v.x;
        xsT[(k0 + 1) * 64 + rs_] = v.y;
        xsT[(k0 + 2) * 64 + rs_] = v.z;
        xsT[(k0 + 3) * 64 + rs_] = v.w;
    }
    __syncthreads();

    const int r0 = (tid >> 4) << 2;
    const int c0 = (tid & 15) << 2;
    float acc[4][4] = {};
#pragma unroll 4
    for (int k = 0; k < 128; ++k) {
        const int sk = ((k >> 2) & 7) << 2;
        const float4 xv = *reinterpret_cast<const float4*>(xsT + k * 64 + (r0 ^ sk));
        const float4 wv = *reinterpret_cast<const float4*>(Ws  + k * 64 + c0);
        const float xr[4] = {xv.x, xv.y, xv.z, xv.w};
        const float wr[4] = {wv.x, wv.y, wv.z, wv.w};
#pragma unroll
        for (int i = 0; i < 4; ++i)
#pragma unroll
            for (int j = 0; j < 4; ++j)
                acc[i][j] = fmaf(xr[i], wr[j], acc[i][j]);
    }

#pragma unroll
    for (int i = 0; i < 4; ++i) {
        const int row = rbase + r0 + i;
        if (row < NN) {
            union { __half2 h[2]; uint2 u; } pk;
            pk.h[0] = __floats2half2_rn(acc[i][0], acc[i][1]);
            pk.h[1] = __floats2half2_rn(acc[i][2], acc[i][3]);
            *reinterpret_cast<uint2*>(h2 + (size_t)row * D + cbase + c0) = pk.u;
        }
    }

    const float4 a1v = *reinterpret_cast<const float4*>(a + cbase + c0);
    const float4 a2v = *reinterpret_cast<const float4*>(a + D + cbase + c0);
    const float a1r[4] = {a1v.x, a1v.y, a1v.z, a1v.w};
    const float a2r[4] = {a2v.x, a2v.y, a2v.z, a2v.w};
    float sp[4], tp[4];
#pragma unroll
    for (int i = 0; i < 4; ++i) {
        sp[i] = 0.f; tp[i] = 0.f;
#pragma unroll
        for (int j = 0; j < 4; ++j) {
            sp[i] = fmaf(acc[i][j], a1r[j], sp[i]);
            tp[i] = fmaf(acc[i][j], a2r[j], tp[i]);
        }
    }
#pragma unroll
    for (int off = 1; off < 16; off <<= 1) {
#pragma unroll
        for (int i = 0; i < 4; ++i) {
            sp[i] += __shfl_xor(sp[i], off);
            tp[i] += __shfl_xor(tp[i], off);
        }
    }
    if ((tid & 15) == 0) {
#pragma unroll
        for (int i = 0; i < 4; ++i) {
            const int row = rbase + r0 + i;
            if (row < NN) {
                atomicAdd(&s[row], sp[i]);
                atomicAdd(&t[row], tp[i]);
            }
        }
    }
}

// ---------------------------------------------------------------------------
// Bucket histogram: bcnt[src>>5] += 1 per edge.
// ---------------------------------------------------------------------------
__global__ __launch_bounds__(256) void hist_kernel(const int* __restrict__ edge,
                                                   int* __restrict__ bcnt) {
    const int e = blockIdx.x * 256 + threadIdx.x;
    if (e < NE) atomicAdd(&bcnt[edge[e] >> BUCK_SHIFT], 1);
}

// ---------------------------------------------------------------------------
// Single-block exclusive scan of 3125 bucket counts (4 chunks of 1024).
// bbase[NBUCK] = NE sentinel; bcur initialized to bbase for slot allocation.
// ---------------------------------------------------------------------------
__global__ __launch_bounds__(1024) void bscan_kernel(const int* __restrict__ bcnt,
                                                     int* __restrict__ bbase,
                                                     int* __restrict__ bcur) {
    __shared__ int sh[1024];
    __shared__ int carry;
    const int t = threadIdx.x;
    if (t == 0) carry = 0;
    __syncthreads();
    for (int c0 = 0; c0 < NBUCK; c0 += 1024) {
        const int i = c0 + t;
        const int v = (i < NBUCK) ? bcnt[i] : 0;
        sh[t] = v;
        __syncthreads();
        for (int off = 1; off < 1024; off <<= 1) {
            const int add = (t >= off) ? sh[t - off] : 0;
            __syncthreads();
            sh[t] += add;
            __syncthreads();
        }
        if (i < NBUCK) {
            const int ex = carry + sh[t] - v;   // exclusive
            bbase[i] = ex;
            bcur[i]  = ex;
        }
        const int total = sh[1023];
        __syncthreads();
        if (t == 0) carry += total;
        __syncthreads();
    }
    if (t == 0) bbase[NBUCK] = NE;
}

// ---------------------------------------------------------------------------
// Per edge: ee = exp(-leaky(s[src]+t[dst])) (coalesced write in edge order);
// allocate bucket slot; write packed (dst | src_local<<27, ee). Writes land
// randomly only within 32-node bucket regions -> tail lines stay in L2 and
// merge (kills R4's 107 MB write amplification).
// ---------------------------------------------------------------------------
__global__ __launch_bounds__(256) void scatter_kernel(const int* __restrict__ edge,
                                                      const float* __restrict__ s,
                                                      const float* __restrict__ t,
                                                      int* __restrict__ bcur,
                                                      int2* __restrict__ bucketed,
                                                      float* __restrict__ ee_out) {
    const int e = blockIdx.x * 256 + threadIdx.x;
    if (e >= NE) return;
    const int src = edge[e];
    const int dst = edge[NE + e];
    const float es = s[src] + t[dst];
    const float lr = es > 0.f ? es : SLOPE * es;
    const float ee = expf(-lr);
    ee_out[e] = ee;
    const int slot = atomicAdd(&bcur[src >> BUCK_SHIFT], 1);  // absolute index
    bucketed[slot] = make_int2(dst | ((src & 31) << 27), __float_as_int(ee));
}

// ---------------------------------------------------------------------------
// One block per bucket: 32x128 fp32 accumulator in LDS (16 KB -> 8 blocks/CU).
// Each wave streams a stride-4 slice of the bucket's edges: wave-uniform pair
// load, 4B half2 row load per lane (64 lanes = full 256B row), two LDS-atomic
// adds into the src_local row. 2-deep unroll for row-load MLP. Epilogue:
// fused ELU + coalesced float4 store of all 32 node rows.
// ---------------------------------------------------------------------------
__global__ __launch_bounds__(256) void gather_kernel(const int2* __restrict__ bucketed,
                                                     const int* __restrict__ bbase,
                                                     const __half* __restrict__ h2,
                                                     float* __restrict__ out) {
    __shared__ float acc[32 * D];   // 16 KB
    const int tid  = threadIdx.x;
    const int b    = blockIdx.x;
    const int wid  = tid >> 6;
    const int lane = tid & 63;

    for (int i = tid; i < 32 * D; i += 256) acc[i] = 0.f;
    __syncthreads();

    const int base = bbase[b];
    const int end  = bbase[b + 1];

#define EDGE_ACC(P, R) {                                                        \
        const float ee = __int_as_float((P).y);                                 \
        const int   sl = ((unsigned)(P).x) >> 27;                               \
        const float2 f = __half22float2(*reinterpret_cast<const __half2*>(&(R))); \
        float* arow = acc + sl * D + lane * 2;                                  \
        atomicAdd(arow,     ee * f.x);                                          \
        atomicAdd(arow + 1, ee * f.y); }

    int j = base + wid;
    for (; j + 4 < end; j += 8) {           // two edges per wave per iter
        const int2 p0 = bucketed[j];
        const int2 p1 = bucketed[j + 4];
        const uint r0 = *reinterpret_cast<const uint*>(h2 + (size_t)(p0.x & 0x1FFFF) * D + lane * 2);
        const uint r1 = *reinterpret_cast<const uint*>(h2 + (size_t)(p1.x & 0x1FFFF) * D + lane * 2);
        EDGE_ACC(p0, r0)
        EDGE_ACC(p1, r1)
    }
    for (; j < end; j += 4) {
        const int2 p0 = bucketed[j];
        const uint r0 = *reinterpret_cast<const uint*>(h2 + (size_t)(p0.x & 0x1FFFF) * D + lane * 2);
        EDGE_ACC(p0, r0)
    }
#undef EDGE_ACC

    __syncthreads();
    const int node0 = b << BUCK_SHIFT;      // all 32 nodes < NN (exact split)
    for (int i = tid; i < 32 * (D / 4); i += 256) {
        const int r  = i >> 5;
        const int c4 = (i & 31) << 2;
        float4 v = *reinterpret_cast<const float4*>(acc + r * D + c4);
        v.x = v.x > 0.f ? v.x : expm1f(v.x);
        v.y = v.y > 0.f ? v.y : expm1f(v.y);
        v.z = v.z > 0.f ? v.z : expm1f(v.z);
        v.w = v.w > 0.f ? v.w : expm1f(v.w);
        *reinterpret_cast<float4*>(out + (size_t)(node0 + r) * D + c4) = v;
    }
}

extern "C" void kernel_launch(void* const* d_in, const int* in_sizes, int n_in,
                              void* d_out, int out_size, void* d_ws, size_t ws_size,
                              hipStream_t stream) {
    const int*   edge = (const int*)d_in[0];   // [2,E] int32
    const float* x    = (const float*)d_in[1]; // [N,128]
    const float* W    = (const float*)d_in[2]; // [128,128]
    const float* a    = (const float*)d_in[3]; // [1,256]

    float* out_hp = (float*)d_out;                  // elu(h') [N,128]
    float* out_ee = (float*)d_out + (size_t)NN * D; // edge_e [E]

    // Workspace (~39.3 MB). Every byte read is written first within this call.
    __half* h2       = (__half*)d_ws;                  // N*128 fp16 (25.6 MB)
    int2*   bucketed = (int2*)(h2 + (size_t)NN * D);   // E pairs (12.8 MB)
    float*  s        = (float*)(bucketed + NE);        // [s|t|bcnt] contiguous (zeroed)
    float*  t        = s + NN;
    int*    bcnt     = (int*)(t + NN);                 // NBUCK
    int*    bbase    = bcnt + NBUCK;                   // NBUCK+1
    int*    bcur     = bbase + NBUCK + 1;              // NBUCK

    hipMemsetAsync(s, 0, (2 * (size_t)NN + NBUCK) * sizeof(float), stream);

    dim3 ggrid((NN + 63) / 64, 2);
    hipLaunchKernelGGL(gemm_xw, ggrid, dim3(256), 0, stream, x, W, a, h2, s, t);
    hipLaunchKernelGGL(hist_kernel, dim3((NE + 255) / 256), dim3(256), 0, stream, edge, bcnt);
    hipLaunchKernelGGL(bscan_kernel, dim3(1), dim3(1024), 0, stream, bcnt, bbase, bcur);
    hipLaunchKernelGGL(scatter_kernel, dim3((NE + 255) / 256), dim3(256), 0, stream,
                       edge, s, t, bcur, bucketed, out_ee);
    hipLaunchKernelGGL(gather_kernel, dim3(NBUCK), dim3(256), 0, stream,
                       bucketed, bbase, h2, out_hp);
}

// Round 7
// 509.471 us; speedup vs baseline: 3.0117x; 3.0117x over previous
//
#include <hip/hip_runtime.h>
#include <hip/hip_fp16.h>
#include <math.h>

// Problem constants (from reference): N nodes, E edges, D features.
constexpr int NN = 100000;
constexpr int NE = 1600000;
constexpr int D  = 128;
constexpr float SLOPE = 0.2f;
constexpr int BUCK_SHIFT = 5;              // 32 nodes per bucket
constexpr int NBUCK = NN >> BUCK_SHIFT;    // 3125, exact (100000 = 3125*32)
constexpr int BCAP = 1024;                 // bucket capacity; mean 512, P(>1024) ~ 1e-86

// ---------------------------------------------------------------------------
// Fused GEMM + s/t + fp16 pack (unchanged — verified R4/R6).
// ---------------------------------------------------------------------------
__global__ __launch_bounds__(256) void gemm_xw(const float* __restrict__ x,
                                               const float* __restrict__ W,
                                               const float* __restrict__ a,
                                               __half* __restrict__ h2,
                                               float* __restrict__ s,
                                               float* __restrict__ t) {
    __shared__ float xsT[128 * 64];
    __shared__ float Ws [128 * 64];
    const int tid   = threadIdx.x;
    const int rbase = blockIdx.x * 64;
    const int cbase = blockIdx.y * 64;

#pragma unroll
    for (int i = 0; i < 8; ++i) {
        const int f = tid + i * 256;
        const int k = f >> 4;
        const int c = (f & 15) << 2;
        const float4 w = *reinterpret_cast<const float4*>(W + k * D + cbase + c);
        *reinterpret_cast<float4*>(Ws + k * 64 + c) = w;
    }
#pragma unroll
    for (int i = 0; i < 8; ++i) {
        const int f  = tid + i * 256;
        const int r  = f >> 5;
        const int c4 = f & 31;
        const int k0 = c4 << 2;
        float4 v = make_float4(0.f, 0.f, 0.f, 0.f);
        const int row = rbase + r;
        if (row < NN) v = *reinterpret_cast<const float4*>(x + (size_t)row * D + k0);
        const int rs_ = r ^ ((c4 & 7) << 2);
        xsT[(k0 + 0) * 64 + rs_] = v.x;
        xsT[(k0 + 1) * 64 + rs_] = v.y;
        xsT[(k0 + 2) * 64 + rs_] = v.z;
        xsT[(k0 + 3) * 64 + rs_] = v.w;
    }
    __syncthreads();

    const int r0 = (tid >> 4) << 2;
    const int c0 = (tid & 15) << 2;
    float acc[4][4] = {};
#pragma unroll 4
    for (int k = 0; k < 128; ++k) {
        const int sk = ((k >> 2) & 7) << 2;
        const float4 xv = *reinterpret_cast<const float4*>(xsT + k * 64 + (r0 ^ sk));
        const float4 wv = *reinterpret_cast<const float4*>(Ws  + k * 64 + c0);
        const float xr[4] = {xv.x, xv.y, xv.z, xv.w};
        const float wr[4] = {wv.x, wv.y, wv.z, wv.w};
#pragma unroll
        for (int i = 0; i < 4; ++i)
#pragma unroll
            for (int j = 0; j < 4; ++j)
                acc[i][j] = fmaf(xr[i], wr[j], acc[i][j]);
    }

#pragma unroll
    for (int i = 0; i < 4; ++i) {
        const int row = rbase + r0 + i;
        if (row < NN) {
            union { __half2 h[2]; uint2 u; } pk;
            pk.h[0] = __floats2half2_rn(acc[i][0], acc[i][1]);
            pk.h[1] = __floats2half2_rn(acc[i][2], acc[i][3]);
            *reinterpret_cast<uint2*>(h2 + (size_t)row * D + cbase + c0) = pk.u;
        }
    }

    const float4 a1v = *reinterpret_cast<const float4*>(a + cbase + c0);
    const float4 a2v = *reinterpret_cast<const float4*>(a + D + cbase + c0);
    const float a1r[4] = {a1v.x, a1v.y, a1v.z, a1v.w};
    const float a2r[4] = {a2v.x, a2v.y, a2v.z, a2v.w};
    float sp[4], tp[4];
#pragma unroll
    for (int i = 0; i < 4; ++i) {
        sp[i] = 0.f; tp[i] = 0.f;
#pragma unroll
        for (int j = 0; j < 4; ++j) {
            sp[i] = fmaf(acc[i][j], a1r[j], sp[i]);
            tp[i] = fmaf(acc[i][j], a2r[j], tp[i]);
        }
    }
#pragma unroll
    for (int off = 1; off < 16; off <<= 1) {
#pragma unroll
        for (int i = 0; i < 4; ++i) {
            sp[i] += __shfl_xor(sp[i], off);
            tp[i] += __shfl_xor(tp[i], off);
        }
    }
    if ((tid & 15) == 0) {
#pragma unroll
        for (int i = 0; i < 4; ++i) {
            const int row = rbase + r0 + i;
            if (row < NN) {
                atomicAdd(&s[row], sp[i]);
                atomicAdd(&t[row], tp[i]);
            }
        }
    }
}

// ---------------------------------------------------------------------------
// Bucket histogram: bcnt[src>>5] += 1 per edge. (unchanged)
// ---------------------------------------------------------------------------
__global__ __launch_bounds__(256) void hist_kernel(const int* __restrict__ edge,
                                                   int* __restrict__ bcnt) {
    const int e = blockIdx.x * 256 + threadIdx.x;
    if (e < NE) atomicAdd(&bcnt[edge[e] >> BUCK_SHIFT], 1);
}

// ---------------------------------------------------------------------------
// Single-block exclusive scan of 3125 bucket counts. (unchanged)
// ---------------------------------------------------------------------------
__global__ __launch_bounds__(1024) void bscan_kernel(const int* __restrict__ bcnt,
                                                     int* __restrict__ bbase,
                                                     int* __restrict__ bcur) {
    __shared__ int sh[1024];
    __shared__ int carry;
    const int t = threadIdx.x;
    if (t == 0) carry = 0;
    __syncthreads();
    for (int c0 = 0; c0 < NBUCK; c0 += 1024) {
        const int i = c0 + t;
        const int v = (i < NBUCK) ? bcnt[i] : 0;
        sh[t] = v;
        __syncthreads();
        for (int off = 1; off < 1024; off <<= 1) {
            const int add = (t >= off) ? sh[t - off] : 0;
            __syncthreads();
            sh[t] += add;
            __syncthreads();
        }
        if (i < NBUCK) {
            const int ex = carry + sh[t] - v;
            bbase[i] = ex;
            bcur[i]  = ex;
        }
        const int total = sh[1023];
        __syncthreads();
        if (t == 0) carry += total;
        __syncthreads();
    }
    if (t == 0) bbase[NBUCK] = NE;
}

// ---------------------------------------------------------------------------
// Per edge: ee write (coalesced), bucket slot alloc, packed pair write.
// Writes confined to 32-node bucket regions -> L2-merged. (unchanged)
// ---------------------------------------------------------------------------
__global__ __launch_bounds__(256) void scatter_kernel(const int* __restrict__ edge,
                                                      const float* __restrict__ s,
                                                      const float* __restrict__ t,
                                                      int* __restrict__ bcur,
                                                      int2* __restrict__ bucketed,
                                                      float* __restrict__ ee_out) {
    const int e = blockIdx.x * 256 + threadIdx.x;
    if (e >= NE) return;
    const int src = edge[e];
    const int dst = edge[NE + e];
    const float es = s[src] + t[dst];
    const float lr = es > 0.f ? es : SLOPE * es;
    const float ee = expf(-lr);
    ee_out[e] = ee;
    const int slot = atomicAdd(&bcur[src >> BUCK_SHIFT], 1);  // absolute index
    bucketed[slot] = make_int2(dst | ((src & 31) << 27), __float_as_int(ee));
}

// ---------------------------------------------------------------------------
// One block per bucket. NO fp atomics (R6's 10x regression was the LDS fp32
// atomicAdd path — SQ_LDS_BANK_CONFLICT==0 showed they never ran as ds ops).
// Phase 1: counting sort of the bucket's pairs into per-node LDS order
//          (registers -> native int LDS histogram -> shfl scan -> LDS slots).
// Phase 2: per node, one HALF-WAVE accumulates sum(ee*h2[dst]) in float4
//          registers (R3-proven structure), 4-deep unroll, fused ELU, store.
// LDS 8.5 KB -> 8 blocks/CU.
// ---------------------------------------------------------------------------
__global__ __launch_bounds__(256) void gather_kernel(const int2* __restrict__ bucketed,
                                                     const int* __restrict__ bbase,
                                                     const __half* __restrict__ h2,
                                                     float* __restrict__ out) {
    __shared__ int2 ps[BCAP];         // 8 KB, pairs in per-node order
    __shared__ int hcnt[32];
    __shared__ int sbase[32];
    __shared__ int scur[32];
    const int tid  = threadIdx.x;
    const int b    = blockIdx.x;
    const int base = bbase[b];
    int n = bbase[b + 1] - base;
    if (n > BCAP) n = BCAP;           // unreachable for this dataset (see header)

    if (tid < 32) hcnt[tid] = 0;
    __syncthreads();

    int2 pr[4];
    int  sl[4];
    int  nmine = 0;
#pragma unroll
    for (int k = 0; k < 4; ++k) {
        const int i = tid + k * 256;
        if (i < n) {
            pr[k] = bucketed[base + i];
            sl[k] = ((unsigned)pr[k].x) >> 27;
            atomicAdd(&hcnt[sl[k]], 1);          // native ds_add_u32
            nmine = k + 1;
        }
    }
    __syncthreads();

    if (tid < 32) {
        const int v = hcnt[tid];
        int incl = v;
#pragma unroll
        for (int off = 1; off < 32; off <<= 1) {
            const int u = __shfl_up(incl, off, 32);
            if (tid >= off) incl += u;
        }
        sbase[tid] = incl - v;                   // exclusive
        scur[tid]  = incl - v;
    }
    __syncthreads();

#pragma unroll
    for (int k = 0; k < 4; ++k) {
        if (k < nmine) {
            const int slot = atomicAdd(&scur[sl[k]], 1);
            ps[slot] = pr[k];
        }
    }
    __syncthreads();

    // Phase 2: half-wave per node; hl*4 halves of the 128-wide row per lane.
    const int hw = tid >> 5;          // 0..7
    const int hl = tid & 31;
    const int node0 = b << BUCK_SHIFT;

#define ROW_FMA(P, R) {                                                         \
        const float ee = __int_as_float((P).y);                                 \
        const float2 f01 = __half22float2(*reinterpret_cast<const __half2*>(&(R).x)); \
        const float2 f23 = __half22float2(*reinterpret_cast<const __half2*>(&(R).y)); \
        acc.x = fmaf(ee, f01.x, acc.x); acc.y = fmaf(ee, f01.y, acc.y);         \
        acc.z = fmaf(ee, f23.x, acc.z); acc.w = fmaf(ee, f23.y, acc.w); }

    for (int r = hw; r < 32; r += 8) {
        const int sb = sbase[r];
        const int sc = hcnt[r];
        float4 acc = make_float4(0.f, 0.f, 0.f, 0.f);
        int k = 0;
        for (; k + 4 <= sc; k += 4) {            // 4 independent row loads in flight
            const int2 p0 = ps[sb + k + 0];
            const int2 p1 = ps[sb + k + 1];
            const int2 p2 = ps[sb + k + 2];
            const int2 p3 = ps[sb + k + 3];
            const uint2 r0 = *reinterpret_cast<const uint2*>(h2 + (size_t)(p0.x & 0x1FFFF) * D + hl * 4);
            const uint2 r1 = *reinterpret_cast<const uint2*>(h2 + (size_t)(p1.x & 0x1FFFF) * D + hl * 4);
            const uint2 r2 = *reinterpret_cast<const uint2*>(h2 + (size_t)(p2.x & 0x1FFFF) * D + hl * 4);
            const uint2 r3 = *reinterpret_cast<const uint2*>(h2 + (size_t)(p3.x & 0x1FFFF) * D + hl * 4);
            ROW_FMA(p0, r0) ROW_FMA(p1, r1) ROW_FMA(p2, r2) ROW_FMA(p3, r3)
        }
        for (; k < sc; ++k) {
            const int2 p0 = ps[sb + k];
            const uint2 r0 = *reinterpret_cast<const uint2*>(h2 + (size_t)(p0.x & 0x1FFFF) * D + hl * 4);
            ROW_FMA(p0, r0)
        }
        acc.x = acc.x > 0.f ? acc.x : expm1f(acc.x);
        acc.y = acc.y > 0.f ? acc.y : expm1f(acc.y);
        acc.z = acc.z > 0.f ? acc.z : expm1f(acc.z);
        acc.w = acc.w > 0.f ? acc.w : expm1f(acc.w);
        *reinterpret_cast<float4*>(out + (size_t)(node0 + r) * D + hl * 4) = acc;
    }
#undef ROW_FMA
}

extern "C" void kernel_launch(void* const* d_in, const int* in_sizes, int n_in,
                              void* d_out, int out_size, void* d_ws, size_t ws_size,
                              hipStream_t stream) {
    const int*   edge = (const int*)d_in[0];   // [2,E] int32
    const float* x    = (const float*)d_in[1]; // [N,128]
    const float* W    = (const float*)d_in[2]; // [128,128]
    const float* a    = (const float*)d_in[3]; // [1,256]

    float* out_hp = (float*)d_out;                  // elu(h') [N,128]
    float* out_ee = (float*)d_out + (size_t)NN * D; // edge_e [E]

    // Workspace (~39.3 MB). Every byte read is written first within this call.
    __half* h2       = (__half*)d_ws;                  // N*128 fp16 (25.6 MB)
    int2*   bucketed = (int2*)(h2 + (size_t)NN * D);   // E pairs (12.8 MB)
    float*  s        = (float*)(bucketed + NE);        // [s|t|bcnt] contiguous (zeroed)
    float*  t        = s + NN;
    int*    bcnt     = (int*)(t + NN);                 // NBUCK
    int*    bbase    = bcnt + NBUCK;                   // NBUCK+1
    int*    bcur     = bbase + NBUCK + 1;              // NBUCK

    hipMemsetAsync(s, 0, (2 * (size_t)NN + NBUCK) * sizeof(float), stream);

    dim3 ggrid((NN + 63) / 64, 2);
    hipLaunchKernelGGL(gemm_xw, ggrid, dim3(256), 0, stream, x, W, a, h2, s, t);
    hipLaunchKernelGGL(hist_kernel, dim3((NE + 255) / 256), dim3(256), 0, stream, edge, bcnt);
    hipLaunchKernelGGL(bscan_kernel, dim3(1), dim3(1024), 0, stream, bcnt, bbase, bcur);
    hipLaunchKernelGGL(scatter_kernel, dim3((NE + 255) / 256), dim3(256), 0, stream,
                       edge, s, t, bcur, bucketed, out_ee);
    hipLaunchKernelGGL(gather_kernel, dim3(NBUCK), dim3(256), 0, stream,
                       bucketed, bbase, h2, out_hp);
}

// Round 9
// 317.998 us; speedup vs baseline: 4.8250x; 1.6021x over previous
//
#include <hip/hip_runtime.h>
#include <hip/hip_fp16.h>
#include <math.h>

// Problem constants (from reference): N nodes, E edges, D features.
constexpr int NN = 100000;
constexpr int NE = 1600000;
constexpr int D  = 128;
constexpr float SLOPE = 0.2f;
constexpr int BUCK_SHIFT = 5;              // 32 nodes per fine bucket
constexpr int NBUCK = NN >> BUCK_SHIFT;    // 3125, exact (100000 = 3125*32)
constexpr int BCAP = 1024;                 // bucket capacity; mean 512, P(>1024) ~ 1e-86
constexpr int CO_SHIFT = 11;               // 2048 nodes per coarse bin
constexpr int NCO = (NN + 2047) >> CO_SHIFT; // 49 coarse bins
constexpr int P1_GRID = (NE + 2047) / 2048;  // 782 blocks, 2048 edges each

// ---------------------------------------------------------------------------
// Fused GEMM + s/t + fp16 pack (unchanged — verified R4/R6/R7).
// ---------------------------------------------------------------------------
__global__ __launch_bounds__(256) void gemm_xw(const float* __restrict__ x,
                                               const float* __restrict__ W,
                                               const float* __restrict__ a,
                                               __half* __restrict__ h2,
                                               float* __restrict__ s,
                                               float* __restrict__ t) {
    __shared__ float xsT[128 * 64];
    __shared__ float Ws [128 * 64];
    const int tid   = threadIdx.x;
    const int rbase = blockIdx.x * 64;
    const int cbase = blockIdx.y * 64;

#pragma unroll
    for (int i = 0; i < 8; ++i) {
        const int f = tid + i * 256;
        const int k = f >> 4;
        const int c = (f & 15) << 2;
        const float4 w = *reinterpret_cast<const float4*>(W + k * D + cbase + c);
        *reinterpret_cast<float4*>(Ws + k * 64 + c) = w;
    }
#pragma unroll
    for (int i = 0; i < 8; ++i) {
        const int f  = tid + i * 256;
        const int r  = f >> 5;
        const int c4 = f & 31;
        const int k0 = c4 << 2;
        float4 v = make_float4(0.f, 0.f, 0.f, 0.f);
        const int row = rbase + r;
        if (row < NN) v = *reinterpret_cast<const float4*>(x + (size_t)row * D + k0);
        const int rs_ = r ^ ((c4 & 7) << 2);
        xsT[(k0 + 0) * 64 + rs_] = v.x;
        xsT[(k0 + 1) * 64 + rs_] = v.y;
        xsT[(k0 + 2) * 64 + rs_] = v.z;
        xsT[(k0 + 3) * 64 + rs_] = v.w;
    }
    __syncthreads();

    const int r0 = (tid >> 4) << 2;
    const int c0 = (tid & 15) << 2;
    float acc[4][4] = {};
#pragma unroll 4
    for (int k = 0; k < 128; ++k) {
        const int sk = ((k >> 2) & 7) << 2;
        const float4 xv = *reinterpret_cast<const float4*>(xsT + k * 64 + (r0 ^ sk));
        const float4 wv = *reinterpret_cast<const float4*>(Ws  + k * 64 + c0);
        const float xr[4] = {xv.x, xv.y, xv.z, xv.w};
        const float wr[4] = {wv.x, wv.y, wv.z, wv.w};
#pragma unroll
        for (int i = 0; i < 4; ++i)
#pragma unroll
            for (int j = 0; j < 4; ++j)
                acc[i][j] = fmaf(xr[i], wr[j], acc[i][j]);
    }

#pragma unroll
    for (int i = 0; i < 4; ++i) {
        const int row = rbase + r0 + i;
        if (row < NN) {
            union { __half2 h[2]; uint2 u; } pk;
            pk.h[0] = __floats2half2_rn(acc[i][0], acc[i][1]);
            pk.h[1] = __floats2half2_rn(acc[i][2], acc[i][3]);
            *reinterpret_cast<uint2*>(h2 + (size_t)row * D + cbase + c0) = pk.u;
        }
    }

    const float4 a1v = *reinterpret_cast<const float4*>(a + cbase + c0);
    const float4 a2v = *reinterpret_cast<const float4*>(a + D + cbase + c0);
    const float a1r[4] = {a1v.x, a1v.y, a1v.z, a1v.w};
    const float a2r[4] = {a2v.x, a2v.y, a2v.z, a2v.w};
    float sp[4], tp[4];
#pragma unroll
    for (int i = 0; i < 4; ++i) {
        sp[i] = 0.f; tp[i] = 0.f;
#pragma unroll
        for (int j = 0; j < 4; ++j) {
            sp[i] = fmaf(acc[i][j], a1r[j], sp[i]);
            tp[i] = fmaf(acc[i][j], a2r[j], tp[i]);
        }
    }
#pragma unroll
    for (int off = 1; off < 16; off <<= 1) {
#pragma unroll
        for (int i = 0; i < 4; ++i) {
            sp[i] += __shfl_xor(sp[i], off);
            tp[i] += __shfl_xor(tp[i], off);
        }
    }
    if ((tid & 15) == 0) {
#pragma unroll
        for (int i = 0; i < 4; ++i) {
            const int row = rbase + r0 + i;
            if (row < NN) {
                atomicAdd(&s[row], sp[i]);
                atomicAdd(&t[row], tp[i]);
            }
        }
    }
}

// ---------------------------------------------------------------------------
// P1a: coarse histogram. Per-block LDS agg -> 49 global atomics per block
// (38K total device atomics vs R7's 1.6M hammering 3125 counters).
// ---------------------------------------------------------------------------
__global__ __launch_bounds__(256) void coarse_hist(const int* __restrict__ edge,
                                                   int* __restrict__ ccnt) {
    __shared__ int lh[NCO];
    const int tid = threadIdx.x;
    if (tid < NCO) lh[tid] = 0;
    __syncthreads();
    const int e0 = blockIdx.x * 2048 + tid;
#pragma unroll
    for (int k = 0; k < 8; ++k) {
        const int e = e0 + k * 256;
        if (e < NE) atomicAdd(&lh[edge[e] >> CO_SHIFT], 1);   // native LDS int atomic
    }
    __syncthreads();
    if (tid < NCO && lh[tid] > 0) atomicAdd(&ccnt[tid], lh[tid]);
}

// ---------------------------------------------------------------------------
// P1b: single-wave exclusive scan of 49 coarse counts; sentinel at [NCO]=NE.
// ---------------------------------------------------------------------------
__global__ __launch_bounds__(64) void coarse_scan(const int* __restrict__ ccnt,
                                                  int* __restrict__ cbase,
                                                  int* __restrict__ ccur) {
    const int tid = threadIdx.x;
    const int v = (tid < NCO) ? ccnt[tid] : 0;
    int incl = v;
#pragma unroll
    for (int off = 1; off < 64; off <<= 1) {
        const int u = __shfl_up(incl, off, 64);
        if (tid >= off) incl += u;
    }
    if (tid <= NCO) cbase[tid] = incl - v;   // tid==NCO lands on total == NE
    if (tid <  NCO) ccur[tid]  = incl - v;
}

// ---------------------------------------------------------------------------
// P1c: coarse partition + ee. Per-block LDS hist -> ONE global atomic per
// (block,bin) reserves a private contiguous run (~42 edges = 336B) -> writes
// are single-block runs, minimal line sharing. Also computes ee (coalesced
// ee_out in edge order) and packs (dst | (src&2047)<<17, ee).
// ---------------------------------------------------------------------------
__global__ __launch_bounds__(256) void partition_coarse(const int* __restrict__ edge,
                                                        const float* __restrict__ s,
                                                        const float* __restrict__ t,
                                                        int* __restrict__ ccur,
                                                        int2* __restrict__ cobuf,
                                                        float* __restrict__ ee_out) {
    __shared__ int lh[NCO];
    __shared__ int lcur[NCO];
    const int tid = threadIdx.x;
    if (tid < NCO) lh[tid] = 0;
    __syncthreads();

    int srcs[8];
    int bins[8];
    const int e0 = blockIdx.x * 2048 + tid;
#pragma unroll
    for (int k = 0; k < 8; ++k) {
        const int e = e0 + k * 256;
        if (e < NE) {
            const int sv = edge[e];
            srcs[k] = sv;
            bins[k] = sv >> CO_SHIFT;
            atomicAdd(&lh[bins[k]], 1);
        } else bins[k] = -1;
    }
    __syncthreads();
    if (tid < NCO) {
        const int c = lh[tid];
        lcur[tid] = (c > 0) ? atomicAdd(&ccur[tid], c) : 0;
    }
    __syncthreads();

#pragma unroll
    for (int k = 0; k < 8; ++k) {
        if (bins[k] >= 0) {
            const int e   = e0 + k * 256;
            const int dst = edge[NE + e];
            const float es = s[srcs[k]] + t[dst];
            const float lr = es > 0.f ? es : SLOPE * es;
            const float ee = expf(-lr);
            ee_out[e] = ee;
            const int slot = atomicAdd(&lcur[bins[k]], 1);    // LDS rank
            cobuf[slot] = make_int2(dst | ((srcs[k] & 2047) << 17), __float_as_int(ee));
        }
    }
}

// ---------------------------------------------------------------------------
// P2: fine partition. ONE block per coarse bin (single writer per fine bucket
// -> partial lines merge in that XCD's L2; kills the 8-XCD interleave that
// kept R7's WRITE_SIZE at 95MB). Stream 1: LDS 64-bin hist. Single-wave scan
// -> fine-bucket bases (written to bbase). Stream 2: scatter via LDS cursors,
// rewriting payload to gather's format (dst | src_local5<<27, ee).
// ---------------------------------------------------------------------------
__global__ __launch_bounds__(1024) void partition_fine(const int2* __restrict__ cobuf,
                                                       const int* __restrict__ cbase,
                                                       int2* __restrict__ bucketed,
                                                       int* __restrict__ bbase) {
    __shared__ int lh[64];
    __shared__ int lcur[64];
    const int c    = blockIdx.x;            // 0..NCO-1
    const int tid  = threadIdx.x;
    const int rbeg = cbase[c];
    const int rend = cbase[c + 1];
    const int nloc = min(64, NBUCK - c * 64);

    if (tid < 64) lh[tid] = 0;
    __syncthreads();
    for (int i = rbeg + tid; i < rend; i += 1024) {
        const int f = (((unsigned)cobuf[i].x) >> 22) & 63;    // (src&2047)>>5
        atomicAdd(&lh[f], 1);
    }
    __syncthreads();
    if (tid < 64) {                          // wave 0: exclusive scan of 64
        const int v = lh[tid];
        int incl = v;
#pragma unroll
        for (int off = 1; off < 64; off <<= 1) {
            const int u = __shfl_up(incl, off, 64);
            if (tid >= off) incl += u;
        }
        const int ex = rbeg + incl - v;
        lcur[tid] = ex;
        if (tid < nloc) bbase[c * 64 + tid] = ex;
    }
    __syncthreads();
    for (int i = rbeg + tid; i < rend; i += 1024) {
        const int2 p = cobuf[i];
        const int f = (((unsigned)p.x) >> 22) & 63;
        const int slot = atomicAdd(&lcur[f], 1);
        bucketed[slot] = make_int2((p.x & 0x1FFFF) | (((p.x >> 17) & 31) << 27), p.y);
    }
    if (c == 0 && tid == 0) bbase[NBUCK] = NE;
}

// ---------------------------------------------------------------------------
// Gather (unchanged from R7 — verified). In-LDS counting sort to per-node
// order, then half-wave register accumulation, fused ELU, coalesced store.
// ---------------------------------------------------------------------------
__global__ __launch_bounds__(256) void gather_kernel(const int2* __restrict__ bucketed,
                                                     const int* __restrict__ bbase,
                                                     const __half* __restrict__ h2,
                                                     float* __restrict__ out) {
    __shared__ int2 ps[BCAP];         // 8 KB, pairs in per-node order
    __shared__ int hcnt[32];
    __shared__ int sbase[32];
    __shared__ int scur[32];
    const int tid  = threadIdx.x;
    const int b    = blockIdx.x;
    const int base = bbase[b];
    int n = bbase[b + 1] - base;
    if (n > BCAP) n = BCAP;           // unreachable for this dataset

    if (tid < 32) hcnt[tid] = 0;
    __syncthreads();

    int2 pr[4];
    int  sl[4];
    int  nmine = 0;
#pragma unroll
    for (int k = 0; k < 4; ++k) {
        const int i = tid + k * 256;
        if (i < n) {
            pr[k] = bucketed[base + i];
            sl[k] = ((unsigned)pr[k].x) >> 27;
            atomicAdd(&hcnt[sl[k]], 1);
            nmine = k + 1;
        }
    }
    __syncthreads();

    if (tid < 32) {
        const int v = hcnt[tid];
        int incl = v;
#pragma unroll
        for (int off = 1; off < 32; off <<= 1) {
            const int u = __shfl_up(incl, off, 32);
            if (tid >= off) incl += u;
        }
        sbase[tid] = incl - v;
        scur[tid]  = incl - v;
    }
    __syncthreads();

#pragma unroll
    for (int k = 0; k < 4; ++k) {
        if (k < nmine) {
            const int slot = atomicAdd(&scur[sl[k]], 1);
            ps[slot] = pr[k];
        }
    }
    __syncthreads();

    const int hw = tid >> 5;          // 0..7 half-waves
    const int hl = tid & 31;
    const int node0 = b << BUCK_SHIFT;

#define ROW_FMA(P, R) {                                                         \
        const float ee = __int_as_float((P).y);                                 \
        const float2 f01 = __half22float2(*reinterpret_cast<const __half2*>(&(R).x)); \
        const float2 f23 = __half22float2(*reinterpret_cast<const __half2*>(&(R).y)); \
        acc.x = fmaf(ee, f01.x, acc.x); acc.y = fmaf(ee, f01.y, acc.y);         \
        acc.z = fmaf(ee, f23.x, acc.z); acc.w = fmaf(ee, f23.y, acc.w); }

    for (int r = hw; r < 32; r += 8) {
        const int sb = sbase[r];
        const int sc = hcnt[r];
        float4 acc = make_float4(0.f, 0.f, 0.f, 0.f);
        int k = 0;
        for (; k + 4 <= sc; k += 4) {
            const int2 p0 = ps[sb + k + 0];
            const int2 p1 = ps[sb + k + 1];
            const int2 p2 = ps[sb + k + 2];
            const int2 p3 = ps[sb + k + 3];
            const uint2 r0 = *reinterpret_cast<const uint2*>(h2 + (size_t)(p0.x & 0x1FFFF) * D + hl * 4);
            const uint2 r1 = *reinterpret_cast<const uint2*>(h2 + (size_t)(p1.x & 0x1FFFF) * D + hl * 4);
            const uint2 r2 = *reinterpret_cast<const uint2*>(h2 + (size_t)(p2.x & 0x1FFFF) * D + hl * 4);
            const uint2 r3 = *reinterpret_cast<const uint2*>(h2 + (size_t)(p3.x & 0x1FFFF) * D + hl * 4);
            ROW_FMA(p0, r0) ROW_FMA(p1, r1) ROW_FMA(p2, r2) ROW_FMA(p3, r3)
        }
        for (; k < sc; ++k) {
            const int2 p0 = ps[sb + k];
            const uint2 r0 = *reinterpret_cast<const uint2*>(h2 + (size_t)(p0.x & 0x1FFFF) * D + hl * 4);
            ROW_FMA(p0, r0)
        }
        acc.x = acc.x > 0.f ? acc.x : expm1f(acc.x);
        acc.y = acc.y > 0.f ? acc.y : expm1f(acc.y);
        acc.z = acc.z > 0.f ? acc.z : expm1f(acc.z);
        acc.w = acc.w > 0.f ? acc.w : expm1f(acc.w);
        *reinterpret_cast<float4*>(out + (size_t)(node0 + r) * D + hl * 4) = acc;
    }
#undef ROW_FMA
}

extern "C" void kernel_launch(void* const* d_in, const int* in_sizes, int n_in,
                              void* d_out, int out_size, void* d_ws, size_t ws_size,
                              hipStream_t stream) {
    const int*   edge = (const int*)d_in[0];   // [2,E] int32
    const float* x    = (const float*)d_in[1]; // [N,128]
    const float* W    = (const float*)d_in[2]; // [128,128]
    const float* a    = (const float*)d_in[3]; // [1,256]

    float* out_hp = (float*)d_out;                  // elu(h') [N,128]
    float* out_ee = (float*)d_out + (size_t)NN * D; // edge_e [E]

    // Workspace (~52 MB). Every byte read is written first within this call.
    __half* h2       = (__half*)d_ws;                  // N*128 fp16 (25.6 MB)
    int2*   cobuf    = (int2*)(h2 + (size_t)NN * D);   // E pairs, coarse order (12.8 MB)
    int2*   bucketed = cobuf + NE;                     // E pairs, fine order (12.8 MB)
    float*  s        = (float*)(bucketed + NE);        // [s|t|ccnt] contiguous (zeroed)
    float*  t        = s + NN;
    int*    ccnt     = (int*)(t + NN);                 // NCO
    int*    cbase    = ccnt + NCO;                     // NCO+1
    int*    ccur     = cbase + NCO + 1;                // NCO
    int*    bbase    = ccur + NCO;                     // NBUCK+1

    hipMemsetAsync(s, 0, (2 * (size_t)NN + NCO) * sizeof(float), stream);

    dim3 ggrid((NN + 63) / 64, 2);
    hipLaunchKernelGGL(gemm_xw, ggrid, dim3(256), 0, stream, x, W, a, h2, s, t);
    hipLaunchKernelGGL(coarse_hist, dim3(P1_GRID), dim3(256), 0, stream, edge, ccnt);
    hipLaunchKernelGGL(coarse_scan, dim3(1), dim3(64), 0, stream, ccnt, cbase, ccur);
    hipLaunchKernelGGL(partition_coarse, dim3(P1_GRID), dim3(256), 0, stream,
                       edge, s, t, ccur, cobuf, out_ee);
    hipLaunchKernelGGL(partition_fine, dim3(NCO), dim3(1024), 0, stream,
                       cobuf, cbase, bucketed, bbase);
    hipLaunchKernelGGL(gather_kernel, dim3(NBUCK), dim3(256), 0, stream,
                       bucketed, bbase, h2, out_hp);
}